// Round 8
// baseline (503.430 us; speedup 1.0000x reference)
//
#include <hip/hip_runtime.h>
#include <hip/hip_bf16.h>
#include <math.h>

#define N_NODES 50000
#define N_EDGES 800000
#define BB 2
#define WFEAT 128
#define DD 64
#define OUTD 128
#define NROWS (BB * N_NODES)      // 100000
#define SCAN_B 256
#define NBLK ((N_NODES + SCAN_B - 1) / SCAN_B)   // 196

#define PROJ_B 12500
#define CVTX_B 6250               // NROWS*WFEAT/8/256
#define CVTW_B 16                 // OUTD*256/8/256
#define HIST_B 3125               // N_EDGES/256
#define PREP_B (PROJ_B + CVTX_B + CVTW_B + HIST_B)

typedef __attribute__((ext_vector_type(8))) short bf16x8;
typedef __attribute__((ext_vector_type(4))) float f32x4;
typedef __attribute__((ext_vector_type(2))) float f32x2;
typedef __attribute__((ext_vector_type(8))) unsigned short ushort8;

#define PRESCALE 2.8853900817779268f   // 2*log2(e)
#define L2E 1.4426950408889634f

static __device__ __forceinline__ unsigned short f2bf(float f) {
    __hip_bfloat16 h = __float2bfloat16(f);
    return *reinterpret_cast<unsigned short*>(&h);
}
static __device__ __forceinline__ float bf_lo(unsigned int w) {
    return __uint_as_float(w << 16);
}
static __device__ __forceinline__ float bf_hi(unsigned int w) {
    return __uint_as_float(w & 0xFFFF0000u);
}
static __device__ __forceinline__ f32x2 up2(unsigned int w) {
    f32x2 r;
    r.x = __uint_as_float(w << 16);
    r.y = __uint_as_float(w & 0xFFFF0000u);
    return r;
}
// 2^x via single HW instruction (v_exp_f32)
static __device__ __forceinline__ float exp2_hw(float x) {
    float r;
    asm("v_exp_f32 %0, %1" : "=v"(r) : "v"(x));
    return r;
}

// ---------------- Mega prep kernel: proj | cvt_x | cvt_fcW | hist by blockIdx range
__global__ __launch_bounds__(256) void prep_kernel(const float* __restrict__ emb,
                                                   const float* __restrict__ Wq,
                                                   const float* __restrict__ Wk,
                                                   unsigned short* __restrict__ eqb,
                                                   unsigned short* __restrict__ ekb,
                                                   const float* __restrict__ x,
                                                   unsigned short* __restrict__ xb,
                                                   const float* __restrict__ fcW,
                                                   unsigned short* __restrict__ fcWb,
                                                   const int* __restrict__ dstp,
                                                   int* __restrict__ deg) {
    int bid = blockIdx.x;
    int tid = threadIdx.x;
    if (bid < PROJ_B) {
        // ---- node projections -> bf16 eq/ek, prescaled by 2*log2e
        __shared__ float wqT[64 * 65];   // wqT[k*65+d] = Wq[d*64+k]
        __shared__ float wkT[64 * 65];
        for (int idx = tid; idx < 4096; idx += 256) {
            int d = idx >> 6, k = idx & 63;
            wqT[k * 65 + d] = Wq[idx];
            wkT[k * 65 + d] = Wk[idx];
        }
        __syncthreads();
        int t = bid * 256 + tid;
        int n = t >> 6, d = t & 63;
        const float4* er4 = (const float4*)(emb + (size_t)n * DD);
        float aq = 0.f, ak = 0.f;
#pragma unroll
        for (int k4 = 0; k4 < 16; ++k4) {
            float4 e = er4[k4];
            int k = k4 * 4;
            aq += e.x * wqT[(k + 0) * 65 + d] + e.y * wqT[(k + 1) * 65 + d]
                + e.z * wqT[(k + 2) * 65 + d] + e.w * wqT[(k + 3) * 65 + d];
            ak += e.x * wkT[(k + 0) * 65 + d] + e.y * wkT[(k + 1) * 65 + d]
                + e.z * wkT[(k + 2) * 65 + d] + e.w * wkT[(k + 3) * 65 + d];
        }
        eqb[t] = f2bf(PRESCALE * aq);
        ekb[t] = f2bf(PRESCALE * ak);
    } else if (bid < PROJ_B + CVTX_B) {
        // ---- x fp32 -> bf16
        int t = (bid - PROJ_B) * 256 + tid;
        const float4* in4 = (const float4*)x;
        float4 a = in4[2 * t], b = in4[2 * t + 1];
        ushort8 o;
        o[0] = f2bf(a.x); o[1] = f2bf(a.y); o[2] = f2bf(a.z); o[3] = f2bf(a.w);
        o[4] = f2bf(b.x); o[5] = f2bf(b.y); o[6] = f2bf(b.z); o[7] = f2bf(b.w);
        *reinterpret_cast<ushort8*>(&xb[8 * t]) = o;
    } else if (bid < PROJ_B + CVTX_B + CVTW_B) {
        // ---- fcW fp32 -> bf16
        int t = (bid - PROJ_B - CVTX_B) * 256 + tid;
        const float4* in4 = (const float4*)fcW;
        float4 a = in4[2 * t], b = in4[2 * t + 1];
        ushort8 o;
        o[0] = f2bf(a.x); o[1] = f2bf(a.y); o[2] = f2bf(a.z); o[3] = f2bf(a.w);
        o[4] = f2bf(b.x); o[5] = f2bf(b.y); o[6] = f2bf(b.z); o[7] = f2bf(b.w);
        *reinterpret_cast<ushort8*>(&fcWb[8 * t]) = o;
    } else {
        // ---- dst-degree histogram
        int e = (bid - PROJ_B - CVTX_B - CVTW_B) * 256 + tid;
        atomicAdd(&deg[dstp[e]], 1);
    }
}

// ---------------- CSR build: scan (+ degree-bin counting sort, folded in)
__global__ void scan_reduce(const int* __restrict__ deg, int* __restrict__ bsum,
                            int* __restrict__ dhist) {
    __shared__ int sh[SCAN_B];
    int i = blockIdx.x * SCAN_B + threadIdx.x;
    int v = (i < N_NODES) ? deg[i] : 0;
    sh[threadIdx.x] = v;
    __syncthreads();
    for (int s = SCAN_B / 2; s; s >>= 1) {
        if (threadIdx.x < s) sh[threadIdx.x] += sh[threadIdx.x + s];
        __syncthreads();
    }
    if (threadIdx.x == 0) bsum[blockIdx.x] = sh[0];
    if (i < N_NODES) atomicAdd(&dhist[v < 255 ? v : 255], 1);
}

// exclusive scans of bsum (NBLK) and dhist (256 bins) in one block
__global__ void scan_bsum(int* __restrict__ bsum, int* __restrict__ dhist,
                          int* __restrict__ dcur) {
    __shared__ int sh[SCAN_B];
    int tid = threadIdx.x;
    int v = (tid < NBLK) ? bsum[tid] : 0;
    sh[tid] = v;
    __syncthreads();
    for (int s = 1; s < SCAN_B; s <<= 1) {
        int t = (tid >= s) ? sh[tid - s] : 0;
        __syncthreads();
        sh[tid] += t;
        __syncthreads();
    }
    if (tid < NBLK) bsum[tid] = sh[tid] - v;   // exclusive
    __syncthreads();
    int d = dhist[tid];
    sh[tid] = d;
    __syncthreads();
    for (int s = 1; s < SCAN_B; s <<= 1) {
        int t = (tid >= s) ? sh[tid - s] : 0;
        __syncthreads();
        sh[tid] += t;
        __syncthreads();
    }
    dcur[tid] = sh[tid] - d;                   // exclusive bin starts
}

__global__ void scan_final(const int* __restrict__ deg, const int* __restrict__ bsum,
                           int* __restrict__ rowptr, int* __restrict__ cursor,
                           int* __restrict__ dcur, int* __restrict__ order) {
    __shared__ int sh[SCAN_B];
    int i = blockIdx.x * SCAN_B + threadIdx.x;
    int v = (i < N_NODES) ? deg[i] : 0;
    sh[threadIdx.x] = v;
    __syncthreads();
    for (int s = 1; s < SCAN_B; s <<= 1) {
        int t = 0;
        if ((int)threadIdx.x >= s) t = sh[threadIdx.x - s];
        __syncthreads();
        sh[threadIdx.x] += t;
        __syncthreads();
    }
    if (i < N_NODES) {
        int excl = sh[threadIdx.x] - v + bsum[blockIdx.x];
        rowptr[i] = excl;
        cursor[i] = excl;
        if (i == N_NODES - 1) rowptr[N_NODES] = excl + v;
        // degree-binned node ordering for load-balanced aggregation
        int pos = atomicAdd(&dcur[v < 255 ? v : 255], 1);
        order[pos] = i;
    }
}

__global__ void scatter_kernel(const int* __restrict__ src, const int* __restrict__ dst,
                               int* __restrict__ cursor, int* __restrict__ src_sorted) {
    int e = blockIdx.x * blockDim.x + threadIdx.x;
    if (e >= N_EDGES) return;
    int d = dst[e];
    int pos = atomicAdd(&cursor[d], 1);
    src_sorted[pos] = src[e];
}

// ---------------- Fused score + softmax + aggregation.
// One wave per dst node (degree-binned order); 4 edges/iter, one per 16-lane group.
// Score: lane hl handles dims 4hl..4hl+3; Σv·tanh = Vtot − 2Σv·r with
// r = 1/(exp2(eq2+ek2)+1); 4-step shfl reduce within the group.
// Agg: lane hl holds feats 8hl..8hl+7 (16B) per batch, f32x2 packed FMA.
__global__ __launch_bounds__(256) void agg_fused(const unsigned short* __restrict__ eqb,
                                                 const unsigned short* __restrict__ ekb,
                                                 const float* __restrict__ v,
                                                 const unsigned short* __restrict__ xb,
                                                 const int* __restrict__ rowptr,
                                                 const int* __restrict__ order,
                                                 const int* __restrict__ src_sorted,
                                                 unsigned short* __restrict__ aggb) {
    int widx = (blockIdx.x * 256 + threadIdx.x) >> 6;
    if (widx >= N_NODES) return;
    int node = order[widx];
    int lane = threadIdx.x & 63;
    int g = lane >> 4, hl = lane & 15;

    uint2 eku = *reinterpret_cast<const uint2*>(ekb + (size_t)node * DD + 4 * hl);
    float k0 = bf_lo(eku.x), k1 = bf_hi(eku.x), k2 = bf_lo(eku.y), k3 = bf_hi(eku.y);
    float4 vv = *reinterpret_cast<const float4*>(v + 4 * hl);
    float vs = vv.x + vv.y + vv.z + vv.w;
    vs += __shfl_xor(vs, 1); vs += __shfl_xor(vs, 2);
    vs += __shfl_xor(vs, 4); vs += __shfl_xor(vs, 8);
    float vtotl2 = vs * L2E;

    int beg = rowptr[node], end = rowptr[node + 1];
    int nIter = (end - beg + 3) >> 2;

    float sum = 0.f;
    f32x2 a0[4] = {}, a1[4] = {};

    for (int i = 0; i < nIter; ++i) {
        int p = beg + 4 * i + g;
        bool valid = p < end;
        int pe = valid ? p : end - 1;
        int s = src_sorted[pe];

        uint2 equ = *reinterpret_cast<const uint2*>(eqb + (size_t)s * DD + 4 * hl);
        float s0 = bf_lo(equ.x) + k0, s1 = bf_hi(equ.x) + k1;
        float s2 = bf_lo(equ.y) + k2, s3 = bf_hi(equ.y) + k3;
        float r =      vv.x * __builtin_amdgcn_rcpf(exp2_hw(s0) + 1.f);
        r = fmaf(vv.y, __builtin_amdgcn_rcpf(exp2_hw(s1) + 1.f), r);
        r = fmaf(vv.z, __builtin_amdgcn_rcpf(exp2_hw(s2) + 1.f), r);
        r = fmaf(vv.w, __builtin_amdgcn_rcpf(exp2_hw(s3) + 1.f), r);
        r += __shfl_xor(r, 1); r += __shfl_xor(r, 2);
        r += __shfl_xor(r, 4); r += __shfl_xor(r, 8);
        float w = exp2_hw(fmaf(-2.f * L2E, r, vtotl2));
        w = valid ? w : 0.f;
        sum += w;

        uint4 u0 = *reinterpret_cast<const uint4*>(xb + (size_t)s * WFEAT + 8 * hl);
        uint4 u1 = *reinterpret_cast<const uint4*>(xb + (size_t)(N_NODES + s) * WFEAT + 8 * hl);
        a0[0] += w * up2(u0.x); a0[1] += w * up2(u0.y);
        a0[2] += w * up2(u0.z); a0[3] += w * up2(u0.w);
        a1[0] += w * up2(u1.x); a1[1] += w * up2(u1.y);
        a1[2] += w * up2(u1.z); a1[3] += w * up2(u1.w);
    }

    // combine the four 16-lane groups
    sum += __shfl_xor(sum, 16); sum += __shfl_xor(sum, 32);
#pragma unroll
    for (int j = 0; j < 4; ++j) {
        a0[j].x += __shfl_xor(a0[j].x, 16); a0[j].x += __shfl_xor(a0[j].x, 32);
        a0[j].y += __shfl_xor(a0[j].y, 16); a0[j].y += __shfl_xor(a0[j].y, 32);
        a1[j].x += __shfl_xor(a1[j].x, 16); a1[j].x += __shfl_xor(a1[j].x, 32);
        a1[j].y += __shfl_xor(a1[j].y, 16); a1[j].y += __shfl_xor(a1[j].y, 32);
    }
    float inv = __builtin_amdgcn_rcpf(sum + 1e-8f);

    if (g < 2) {
        float c0 = (g ? a1[0].x : a0[0].x) * inv, c1 = (g ? a1[0].y : a0[0].y) * inv;
        float c2 = (g ? a1[1].x : a0[1].x) * inv, c3 = (g ? a1[1].y : a0[1].y) * inv;
        float c4 = (g ? a1[2].x : a0[2].x) * inv, c5 = (g ? a1[2].y : a0[2].y) * inv;
        float c6 = (g ? a1[3].x : a0[3].x) * inv, c7 = (g ? a1[3].y : a0[3].y) * inv;
        uint4 o;
        o.x = (unsigned int)f2bf(c0) | ((unsigned int)f2bf(c1) << 16);
        o.y = (unsigned int)f2bf(c2) | ((unsigned int)f2bf(c3) << 16);
        o.z = (unsigned int)f2bf(c4) | ((unsigned int)f2bf(c5) << 16);
        o.w = (unsigned int)f2bf(c6) | ((unsigned int)f2bf(c7) << 16);
        size_t row = g ? (size_t)(N_NODES + node) : (size_t)node;
        *reinterpret_cast<uint4*>(&aggb[row * WFEAT + 8 * hl]) = o;
    }
}

// ---------------- out = relu([x, agg] @ fcW^T + fcb) via bf16 MFMA
__global__ __launch_bounds__(256) void fc_mfma(const unsigned short* __restrict__ xb,
                                               const unsigned short* __restrict__ aggb,
                                               const unsigned short* __restrict__ fcWb,
                                               const float* __restrict__ fcb,
                                               float* __restrict__ out) {
    __shared__ unsigned short As[128 * 64];   // 16 KB, swizzled [r][k]
    __shared__ unsigned short Bs[128 * 64];   // 16 KB, swizzled [n][k]
    int tid = threadIdx.x;
    int wave = tid >> 6, lane = tid & 63;
    int wm = wave >> 1, wn = wave & 1;
    int row0 = blockIdx.x * 128;

    f32x4 acc[4][4] = {};

    for (int ks = 0; ks < 4; ++ks) {
        const unsigned short* Asrc = (ks < 2) ? xb : aggb;
        int kbase = (ks & 1) * 64;
        __syncthreads();
#pragma unroll
        for (int c = 0; c < 4; ++c) {
            int idx = (c * 256 + tid) * 8;       // element idx in 128x64 tile
            int r = idx >> 6, k = idx & 63;
            int row = row0 + r;
            ulonglong2 val = make_ulonglong2(0ull, 0ull);
            if (row < NROWS)
                val = *reinterpret_cast<const ulonglong2*>(&Asrc[(size_t)row * WFEAT + kbase + k]);
            int byte = (r * 128 + k * 2) ^ ((r & 7) << 4);
            *reinterpret_cast<ulonglong2*>(reinterpret_cast<char*>(As) + byte) = val;

            ulonglong2 wv = *reinterpret_cast<const ulonglong2*>(&fcWb[(size_t)r * 256 + ks * 64 + k]);
            *reinterpret_cast<ulonglong2*>(reinterpret_cast<char*>(Bs) + byte) = wv;
        }
        __syncthreads();
#pragma unroll
        for (int kk = 0; kk < 2; ++kk) {
            bf16x8 a[4], b[4];
#pragma unroll
            for (int m = 0; m < 4; ++m) {
                int r = wm * 64 + m * 16 + (lane & 15);
                int k = kk * 32 + (lane >> 4) * 8;
                int byte = (r * 128 + k * 2) ^ ((r & 7) << 4);
                a[m] = *reinterpret_cast<bf16x8*>(reinterpret_cast<char*>(As) + byte);
            }
#pragma unroll
            for (int n = 0; n < 4; ++n) {
                int cn = wn * 64 + n * 16 + (lane & 15);
                int k = kk * 32 + (lane >> 4) * 8;
                int byte = (cn * 128 + k * 2) ^ ((cn & 7) << 4);
                b[n] = *reinterpret_cast<bf16x8*>(reinterpret_cast<char*>(Bs) + byte);
            }
#pragma unroll
            for (int m = 0; m < 4; ++m)
#pragma unroll
                for (int n = 0; n < 4; ++n)
                    acc[m][n] = __builtin_amdgcn_mfma_f32_16x16x32_bf16(a[m], b[n], acc[m][n], 0, 0, 0);
        }
    }
    // C/D layout: col = lane&15, row = (lane>>4)*4 + j
#pragma unroll
    for (int m = 0; m < 4; ++m) {
#pragma unroll
        for (int n = 0; n < 4; ++n) {
            int col = wn * 64 + n * 16 + (lane & 15);
            float bias = fcb[col];
#pragma unroll
            for (int j = 0; j < 4; ++j) {
                int row = row0 + wm * 64 + m * 16 + (lane >> 4) * 4 + j;
                if (row < NROWS)
                    out[(size_t)row * OUTD + col] = fmaxf(acc[m][n][j] + bias, 0.f);
            }
        }
    }
}

extern "C" void kernel_launch(void* const* d_in, const int* in_sizes, int n_in,
                              void* d_out, int out_size, void* d_ws, size_t ws_size,
                              hipStream_t stream) {
    const float* x    = (const float*)d_in[0];
    const float* emb  = (const float*)d_in[1];
    const int*   eidx = (const int*)d_in[2];
    const float* Wq   = (const float*)d_in[3];
    const float* Wk   = (const float*)d_in[4];
    const float* v    = (const float*)d_in[5];
    const float* fcW  = (const float*)d_in[6];
    const float* fcb  = (const float*)d_in[7];
    float* out = (float*)d_out;

    char* ws = (char*)d_ws;
    unsigned short* eqb  = (unsigned short*)ws;                  ws += (size_t)N_NODES * DD * 2;
    unsigned short* ekb  = (unsigned short*)ws;                  ws += (size_t)N_NODES * DD * 2;
    unsigned short* xb   = (unsigned short*)ws;                  ws += (size_t)NROWS * WFEAT * 2;
    unsigned short* aggb = (unsigned short*)ws;                  ws += (size_t)NROWS * WFEAT * 2;
    unsigned short* fcWb = (unsigned short*)ws;                  ws += (size_t)OUTD * 256 * 2;
    int* deg        = (int*)ws;                                  ws += (size_t)N_NODES * 4;
    int* dhist      = (int*)ws;                                  ws += 256 * 4;   // adjacent to deg: one memset
    int* rowptr     = (int*)ws;                                  ws += (size_t)(N_NODES + 1) * 4 + 12;
    int* cursor     = (int*)ws;                                  ws += (size_t)N_NODES * 4;
    int* bsum       = (int*)ws;                                  ws += 256 * 4;
    int* dcur       = (int*)ws;                                  ws += 256 * 4;
    int* order      = (int*)ws;                                  ws += (size_t)N_NODES * 4;
    int* src_sorted = (int*)ws;

    const int* srcp = eidx;
    const int* dstp = eidx + N_EDGES;

    hipMemsetAsync(deg, 0, (size_t)(N_NODES + 256) * sizeof(int), stream);  // deg + dhist

    prep_kernel<<<PREP_B, 256, 0, stream>>>(emb, Wq, Wk, eqb, ekb, x, xb, fcW, fcWb, dstp, deg);
    scan_reduce<<<NBLK, SCAN_B, 0, stream>>>(deg, bsum, dhist);
    scan_bsum<<<1, SCAN_B, 0, stream>>>(bsum, dhist, dcur);
    scan_final<<<NBLK, SCAN_B, 0, stream>>>(deg, bsum, rowptr, cursor, dcur, order);
    scatter_kernel<<<(N_EDGES + 255) / 256, 256, 0, stream>>>(srcp, dstp, cursor, src_sorted);
    agg_fused<<<(N_NODES * 64 + 255) / 256, 256, 0, stream>>>(eqb, ekb, v, xb, rowptr,
                                                              order, src_sorted, aggb);
    fc_mfma<<<(NROWS + 127) / 128, 256, 0, stream>>>(xb, aggb, fcWb, fcb, out);
}

// Round 9
// 246.854 us; speedup vs baseline: 2.0394x; 2.0394x over previous
//
#include <hip/hip_runtime.h>
#include <hip/hip_bf16.h>
#include <math.h>

#define N_NODES 50000
#define N_EDGES 800000
#define BB 2
#define WFEAT 128
#define DD 64
#define OUTD 128
#define NROWS (BB * N_NODES)      // 100000
#define SCAN_B 256
#define NBLK ((N_NODES + SCAN_B - 1) / SCAN_B)   // 196

#define PROJ_B 12500
#define CVTX_B 6250               // NROWS*WFEAT/8/256
#define CVTW_B 16                 // OUTD*256/8/256
#define HIST_B 3125               // N_EDGES/256
#define PREP_B (PROJ_B + CVTX_B + CVTW_B + HIST_B)

typedef __attribute__((ext_vector_type(8))) short bf16x8;
typedef __attribute__((ext_vector_type(4))) float f32x4;
typedef __attribute__((ext_vector_type(2))) float f32x2;
typedef __attribute__((ext_vector_type(8))) unsigned short ushort8;

#define PRESCALE 2.8853900817779268f   // 2*log2(e)
#define L2E 1.4426950408889634f

static __device__ __forceinline__ unsigned short f2bf(float f) {
    __hip_bfloat16 h = __float2bfloat16(f);
    return *reinterpret_cast<unsigned short*>(&h);
}
static __device__ __forceinline__ float bf_lo(unsigned int w) {
    return __uint_as_float(w << 16);
}
static __device__ __forceinline__ float bf_hi(unsigned int w) {
    return __uint_as_float(w & 0xFFFF0000u);
}
static __device__ __forceinline__ f32x2 up2(unsigned int w) {
    f32x2 r;
    r.x = __uint_as_float(w << 16);
    r.y = __uint_as_float(w & 0xFFFF0000u);
    return r;
}
// 2^x via single HW instruction (v_exp_f32)
static __device__ __forceinline__ float exp2_hw(float x) {
    float r;
    asm("v_exp_f32 %0, %1" : "=v"(r) : "v"(x));
    return r;
}

// ---------------- Mega prep kernel: proj | cvt_x | cvt_fcW | hist by blockIdx range
__global__ __launch_bounds__(256) void prep_kernel(const float* __restrict__ emb,
                                                   const float* __restrict__ Wq,
                                                   const float* __restrict__ Wk,
                                                   unsigned short* __restrict__ eqb,
                                                   unsigned short* __restrict__ ekb,
                                                   const float* __restrict__ x,
                                                   unsigned short* __restrict__ xb,
                                                   const float* __restrict__ fcW,
                                                   unsigned short* __restrict__ fcWb,
                                                   const int* __restrict__ dstp,
                                                   int* __restrict__ deg) {
    int bid = blockIdx.x;
    int tid = threadIdx.x;
    if (bid < PROJ_B) {
        // ---- node projections -> bf16 eq/ek, prescaled by 2*log2e
        __shared__ float wqT[64 * 65];   // wqT[k*65+d] = Wq[d*64+k]
        __shared__ float wkT[64 * 65];
        for (int idx = tid; idx < 4096; idx += 256) {
            int d = idx >> 6, k = idx & 63;
            wqT[k * 65 + d] = Wq[idx];
            wkT[k * 65 + d] = Wk[idx];
        }
        __syncthreads();
        int t = bid * 256 + tid;
        int n = t >> 6, d = t & 63;
        const float4* er4 = (const float4*)(emb + (size_t)n * DD);
        float aq = 0.f, ak = 0.f;
#pragma unroll
        for (int k4 = 0; k4 < 16; ++k4) {
            float4 e = er4[k4];
            int k = k4 * 4;
            aq += e.x * wqT[(k + 0) * 65 + d] + e.y * wqT[(k + 1) * 65 + d]
                + e.z * wqT[(k + 2) * 65 + d] + e.w * wqT[(k + 3) * 65 + d];
            ak += e.x * wkT[(k + 0) * 65 + d] + e.y * wkT[(k + 1) * 65 + d]
                + e.z * wkT[(k + 2) * 65 + d] + e.w * wkT[(k + 3) * 65 + d];
        }
        eqb[t] = f2bf(PRESCALE * aq);
        ekb[t] = f2bf(PRESCALE * ak);
    } else if (bid < PROJ_B + CVTX_B) {
        // ---- x fp32 -> bf16
        int t = (bid - PROJ_B) * 256 + tid;
        const float4* in4 = (const float4*)x;
        float4 a = in4[2 * t], b = in4[2 * t + 1];
        ushort8 o;
        o[0] = f2bf(a.x); o[1] = f2bf(a.y); o[2] = f2bf(a.z); o[3] = f2bf(a.w);
        o[4] = f2bf(b.x); o[5] = f2bf(b.y); o[6] = f2bf(b.z); o[7] = f2bf(b.w);
        *reinterpret_cast<ushort8*>(&xb[8 * t]) = o;
    } else if (bid < PROJ_B + CVTX_B + CVTW_B) {
        // ---- fcW fp32 -> bf16
        int t = (bid - PROJ_B - CVTX_B) * 256 + tid;
        const float4* in4 = (const float4*)fcW;
        float4 a = in4[2 * t], b = in4[2 * t + 1];
        ushort8 o;
        o[0] = f2bf(a.x); o[1] = f2bf(a.y); o[2] = f2bf(a.z); o[3] = f2bf(a.w);
        o[4] = f2bf(b.x); o[5] = f2bf(b.y); o[6] = f2bf(b.z); o[7] = f2bf(b.w);
        *reinterpret_cast<ushort8*>(&fcWb[8 * t]) = o;
    } else {
        // ---- dst-degree histogram
        int e = (bid - PROJ_B - CVTX_B - CVTW_B) * 256 + tid;
        atomicAdd(&deg[dstp[e]], 1);
    }
}

// ---------------- CSR build: histogram -> scan -> scatter
__global__ void scan_reduce(const int* __restrict__ deg, int* __restrict__ bsum) {
    __shared__ int sh[SCAN_B];
    int i = blockIdx.x * SCAN_B + threadIdx.x;
    sh[threadIdx.x] = (i < N_NODES) ? deg[i] : 0;
    __syncthreads();
    for (int s = SCAN_B / 2; s; s >>= 1) {
        if (threadIdx.x < s) sh[threadIdx.x] += sh[threadIdx.x + s];
        __syncthreads();
    }
    if (threadIdx.x == 0) bsum[blockIdx.x] = sh[0];
}

// parallel exclusive scan over NBLK block sums (single 256-thread block)
__global__ void scan_bsum(int* __restrict__ bsum) {
    __shared__ int sh[SCAN_B];
    int tid = threadIdx.x;
    int v = (tid < NBLK) ? bsum[tid] : 0;
    sh[tid] = v;
    __syncthreads();
    for (int s = 1; s < SCAN_B; s <<= 1) {
        int t = (tid >= s) ? sh[tid - s] : 0;
        __syncthreads();
        sh[tid] += t;
        __syncthreads();
    }
    if (tid < NBLK) bsum[tid] = sh[tid] - v;   // exclusive
}

__global__ void scan_final(const int* __restrict__ deg, const int* __restrict__ bsum,
                           int* __restrict__ rowptr, int* __restrict__ cursor) {
    __shared__ int sh[SCAN_B];
    int i = blockIdx.x * SCAN_B + threadIdx.x;
    int v = (i < N_NODES) ? deg[i] : 0;
    sh[threadIdx.x] = v;
    __syncthreads();
    for (int s = 1; s < SCAN_B; s <<= 1) {
        int t = 0;
        if ((int)threadIdx.x >= s) t = sh[threadIdx.x - s];
        __syncthreads();
        sh[threadIdx.x] += t;
        __syncthreads();
    }
    if (i < N_NODES) {
        int excl = sh[threadIdx.x] - v + bsum[blockIdx.x];
        rowptr[i] = excl;
        cursor[i] = excl;
        if (i == N_NODES - 1) rowptr[N_NODES] = excl + v;
    }
}

__global__ void scatter_kernel(const int* __restrict__ src, const int* __restrict__ dst,
                               int* __restrict__ cursor, int* __restrict__ src_sorted) {
    int e = blockIdx.x * blockDim.x + threadIdx.x;
    if (e >= N_EDGES) return;
    int d = dst[e];
    int pos = atomicAdd(&cursor[d], 1);
    src_sorted[pos] = src[e];
}

// ---------------- Fused score + softmax + aggregation.
// One wave per dst node; 4 edges/iter, one per 16-lane group.
// Score: lane hl handles dims 4hl..4hl+3; Σv·tanh = Vtot − 2Σv·r with
// r = 1/(exp2(eq2+ek2)+1); 4-step shfl reduce within the group.
// Agg: lane hl holds feats 8hl..8hl+7 (16B) per batch, f32x2 packed FMA.
__global__ __launch_bounds__(256) void agg_fused(const unsigned short* __restrict__ eqb,
                                                 const unsigned short* __restrict__ ekb,
                                                 const float* __restrict__ v,
                                                 const unsigned short* __restrict__ xb,
                                                 const int* __restrict__ rowptr,
                                                 const int* __restrict__ src_sorted,
                                                 unsigned short* __restrict__ aggb) {
    int node = (blockIdx.x * 256 + threadIdx.x) >> 6;
    if (node >= N_NODES) return;
    int lane = threadIdx.x & 63;
    int g = lane >> 4, hl = lane & 15;

    uint2 eku = *reinterpret_cast<const uint2*>(ekb + (size_t)node * DD + 4 * hl);
    float k0 = bf_lo(eku.x), k1 = bf_hi(eku.x), k2 = bf_lo(eku.y), k3 = bf_hi(eku.y);
    float4 vv = *reinterpret_cast<const float4*>(v + 4 * hl);
    float vs = vv.x + vv.y + vv.z + vv.w;
    vs += __shfl_xor(vs, 1); vs += __shfl_xor(vs, 2);
    vs += __shfl_xor(vs, 4); vs += __shfl_xor(vs, 8);
    float vtotl2 = vs * L2E;

    int beg = rowptr[node], end = rowptr[node + 1];
    int nIter = (end - beg + 3) >> 2;

    float sum = 0.f;
    f32x2 a0[4] = {}, a1[4] = {};

    for (int i = 0; i < nIter; ++i) {
        int p = beg + 4 * i + g;
        bool valid = p < end;
        int pe = valid ? p : end - 1;
        int s = src_sorted[pe];

        uint2 equ = *reinterpret_cast<const uint2*>(eqb + (size_t)s * DD + 4 * hl);
        float s0 = bf_lo(equ.x) + k0, s1 = bf_hi(equ.x) + k1;
        float s2 = bf_lo(equ.y) + k2, s3 = bf_hi(equ.y) + k3;
        float r =      vv.x * __builtin_amdgcn_rcpf(exp2_hw(s0) + 1.f);
        r = fmaf(vv.y, __builtin_amdgcn_rcpf(exp2_hw(s1) + 1.f), r);
        r = fmaf(vv.z, __builtin_amdgcn_rcpf(exp2_hw(s2) + 1.f), r);
        r = fmaf(vv.w, __builtin_amdgcn_rcpf(exp2_hw(s3) + 1.f), r);
        r += __shfl_xor(r, 1); r += __shfl_xor(r, 2);
        r += __shfl_xor(r, 4); r += __shfl_xor(r, 8);
        float w = exp2_hw(fmaf(-2.f * L2E, r, vtotl2));
        w = valid ? w : 0.f;
        sum += w;

        uint4 u0 = *reinterpret_cast<const uint4*>(xb + (size_t)s * WFEAT + 8 * hl);
        uint4 u1 = *reinterpret_cast<const uint4*>(xb + (size_t)(N_NODES + s) * WFEAT + 8 * hl);
        a0[0] += w * up2(u0.x); a0[1] += w * up2(u0.y);
        a0[2] += w * up2(u0.z); a0[3] += w * up2(u0.w);
        a1[0] += w * up2(u1.x); a1[1] += w * up2(u1.y);
        a1[2] += w * up2(u1.z); a1[3] += w * up2(u1.w);
    }

    // combine the four 16-lane groups
    sum += __shfl_xor(sum, 16); sum += __shfl_xor(sum, 32);
#pragma unroll
    for (int j = 0; j < 4; ++j) {
        a0[j].x += __shfl_xor(a0[j].x, 16); a0[j].x += __shfl_xor(a0[j].x, 32);
        a0[j].y += __shfl_xor(a0[j].y, 16); a0[j].y += __shfl_xor(a0[j].y, 32);
        a1[j].x += __shfl_xor(a1[j].x, 16); a1[j].x += __shfl_xor(a1[j].x, 32);
        a1[j].y += __shfl_xor(a1[j].y, 16); a1[j].y += __shfl_xor(a1[j].y, 32);
    }
    float inv = __builtin_amdgcn_rcpf(sum + 1e-8f);

    if (g < 2) {
        float c0 = (g ? a1[0].x : a0[0].x) * inv, c1 = (g ? a1[0].y : a0[0].y) * inv;
        float c2 = (g ? a1[1].x : a0[1].x) * inv, c3 = (g ? a1[1].y : a0[1].y) * inv;
        float c4 = (g ? a1[2].x : a0[2].x) * inv, c5 = (g ? a1[2].y : a0[2].y) * inv;
        float c6 = (g ? a1[3].x : a0[3].x) * inv, c7 = (g ? a1[3].y : a0[3].y) * inv;
        uint4 o;
        o.x = (unsigned int)f2bf(c0) | ((unsigned int)f2bf(c1) << 16);
        o.y = (unsigned int)f2bf(c2) | ((unsigned int)f2bf(c3) << 16);
        o.z = (unsigned int)f2bf(c4) | ((unsigned int)f2bf(c5) << 16);
        o.w = (unsigned int)f2bf(c6) | ((unsigned int)f2bf(c7) << 16);
        size_t row = g ? (size_t)(N_NODES + node) : (size_t)node;
        *reinterpret_cast<uint4*>(&aggb[row * WFEAT + 8 * hl]) = o;
    }
}

// ---------------- out = relu([x, agg] @ fcW^T + fcb) via bf16 MFMA
__global__ __launch_bounds__(256) void fc_mfma(const unsigned short* __restrict__ xb,
                                               const unsigned short* __restrict__ aggb,
                                               const unsigned short* __restrict__ fcWb,
                                               const float* __restrict__ fcb,
                                               float* __restrict__ out) {
    __shared__ unsigned short As[128 * 64];   // 16 KB, swizzled [r][k]
    __shared__ unsigned short Bs[128 * 64];   // 16 KB, swizzled [n][k]
    int tid = threadIdx.x;
    int wave = tid >> 6, lane = tid & 63;
    int wm = wave >> 1, wn = wave & 1;
    int row0 = blockIdx.x * 128;

    f32x4 acc[4][4] = {};

    for (int ks = 0; ks < 4; ++ks) {
        const unsigned short* Asrc = (ks < 2) ? xb : aggb;
        int kbase = (ks & 1) * 64;
        __syncthreads();
#pragma unroll
        for (int c = 0; c < 4; ++c) {
            int idx = (c * 256 + tid) * 8;       // element idx in 128x64 tile
            int r = idx >> 6, k = idx & 63;
            int row = row0 + r;
            ulonglong2 val = make_ulonglong2(0ull, 0ull);
            if (row < NROWS)
                val = *reinterpret_cast<const ulonglong2*>(&Asrc[(size_t)row * WFEAT + kbase + k]);
            int byte = (r * 128 + k * 2) ^ ((r & 7) << 4);
            *reinterpret_cast<ulonglong2*>(reinterpret_cast<char*>(As) + byte) = val;

            ulonglong2 wv = *reinterpret_cast<const ulonglong2*>(&fcWb[(size_t)r * 256 + ks * 64 + k]);
            *reinterpret_cast<ulonglong2*>(reinterpret_cast<char*>(Bs) + byte) = wv;
        }
        __syncthreads();
#pragma unroll
        for (int kk = 0; kk < 2; ++kk) {
            bf16x8 a[4], b[4];
#pragma unroll
            for (int m = 0; m < 4; ++m) {
                int r = wm * 64 + m * 16 + (lane & 15);
                int k = kk * 32 + (lane >> 4) * 8;
                int byte = (r * 128 + k * 2) ^ ((r & 7) << 4);
                a[m] = *reinterpret_cast<bf16x8*>(reinterpret_cast<char*>(As) + byte);
            }
#pragma unroll
            for (int n = 0; n < 4; ++n) {
                int cn = wn * 64 + n * 16 + (lane & 15);
                int k = kk * 32 + (lane >> 4) * 8;
                int byte = (cn * 128 + k * 2) ^ ((cn & 7) << 4);
                b[n] = *reinterpret_cast<bf16x8*>(reinterpret_cast<char*>(Bs) + byte);
            }
#pragma unroll
            for (int m = 0; m < 4; ++m)
#pragma unroll
                for (int n = 0; n < 4; ++n)
                    acc[m][n] = __builtin_amdgcn_mfma_f32_16x16x32_bf16(a[m], b[n], acc[m][n], 0, 0, 0);
        }
    }
    // C/D layout: col = lane&15, row = (lane>>4)*4 + j
#pragma unroll
    for (int m = 0; m < 4; ++m) {
#pragma unroll
        for (int n = 0; n < 4; ++n) {
            int col = wn * 64 + n * 16 + (lane & 15);
            float bias = fcb[col];
#pragma unroll
            for (int j = 0; j < 4; ++j) {
                int row = row0 + wm * 64 + m * 16 + (lane >> 4) * 4 + j;
                if (row < NROWS)
                    out[(size_t)row * OUTD + col] = fmaxf(acc[m][n][j] + bias, 0.f);
            }
        }
    }
}

extern "C" void kernel_launch(void* const* d_in, const int* in_sizes, int n_in,
                              void* d_out, int out_size, void* d_ws, size_t ws_size,
                              hipStream_t stream) {
    const float* x    = (const float*)d_in[0];
    const float* emb  = (const float*)d_in[1];
    const int*   eidx = (const int*)d_in[2];
    const float* Wq   = (const float*)d_in[3];
    const float* Wk   = (const float*)d_in[4];
    const float* v    = (const float*)d_in[5];
    const float* fcW  = (const float*)d_in[6];
    const float* fcb  = (const float*)d_in[7];
    float* out = (float*)d_out;

    char* ws = (char*)d_ws;
    unsigned short* eqb  = (unsigned short*)ws;                  ws += (size_t)N_NODES * DD * 2;
    unsigned short* ekb  = (unsigned short*)ws;                  ws += (size_t)N_NODES * DD * 2;
    unsigned short* xb   = (unsigned short*)ws;                  ws += (size_t)NROWS * WFEAT * 2;
    unsigned short* aggb = (unsigned short*)ws;                  ws += (size_t)NROWS * WFEAT * 2;
    unsigned short* fcWb = (unsigned short*)ws;                  ws += (size_t)OUTD * 256 * 2;
    int* deg        = (int*)ws;                                  ws += (size_t)N_NODES * 4;
    int* rowptr     = (int*)ws;                                  ws += (size_t)(N_NODES + 1) * 4 + 12;
    int* cursor     = (int*)ws;                                  ws += (size_t)N_NODES * 4;
    int* bsum       = (int*)ws;                                  ws += 256 * 4;
    int* src_sorted = (int*)ws;

    const int* srcp = eidx;
    const int* dstp = eidx + N_EDGES;

    hipMemsetAsync(deg, 0, (size_t)N_NODES * sizeof(int), stream);

    prep_kernel<<<PREP_B, 256, 0, stream>>>(emb, Wq, Wk, eqb, ekb, x, xb, fcW, fcWb, dstp, deg);
    scan_reduce<<<NBLK, SCAN_B, 0, stream>>>(deg, bsum);
    scan_bsum<<<1, SCAN_B, 0, stream>>>(bsum);
    scan_final<<<NBLK, SCAN_B, 0, stream>>>(deg, bsum, rowptr, cursor);
    scatter_kernel<<<(N_EDGES + 255) / 256, 256, 0, stream>>>(srcp, dstp, cursor, src_sorted);
    agg_fused<<<(N_NODES * 64 + 255) / 256, 256, 0, stream>>>(eqb, ekb, v, xb, rowptr,
                                                              src_sorted, aggb);
    fc_mfma<<<(NROWS + 127) / 128, 256, 0, stream>>>(xb, aggb, fcWb, fcb, out);
}

// Round 10
// 186.151 us; speedup vs baseline: 2.7044x; 1.3261x over previous
//
#include <hip/hip_runtime.h>
#include <hip/hip_bf16.h>
#include <math.h>

#define N_NODES 50000
#define N_EDGES 800000
#define BB 2
#define WFEAT 128
#define DD 64
#define OUTD 128
#define NROWS (BB * N_NODES)      // 100000
#define SCAN_B 256
#define NBLK ((N_NODES + SCAN_B - 1) / SCAN_B)   // 196

#define CVTX_B 6250               // NROWS*WFEAT/8/256
#define CVTW_B 16                 // OUTD*256/8/256
#define HIST_B 3125               // N_EDGES/256
#define PREP_B (CVTX_B + CVTW_B + HIST_B)
#define PROJ_TB ((N_NODES + 127) / 128)          // 391

typedef __attribute__((ext_vector_type(8))) short bf16x8;
typedef __attribute__((ext_vector_type(4))) float f32x4;
typedef __attribute__((ext_vector_type(2))) float f32x2;
typedef __attribute__((ext_vector_type(8))) unsigned short ushort8;

#define PRESCALE 2.8853900817779268f   // 2*log2(e)
#define L2E 1.4426950408889634f

static __device__ __forceinline__ unsigned short f2bf(float f) {
    __hip_bfloat16 h = __float2bfloat16(f);
    return *reinterpret_cast<unsigned short*>(&h);
}
static __device__ __forceinline__ float bf_lo(unsigned int w) {
    return __uint_as_float(w << 16);
}
static __device__ __forceinline__ float bf_hi(unsigned int w) {
    return __uint_as_float(w & 0xFFFF0000u);
}
static __device__ __forceinline__ f32x2 up2(unsigned int w) {
    f32x2 r;
    r.x = __uint_as_float(w << 16);
    r.y = __uint_as_float(w & 0xFFFF0000u);
    return r;
}
// 2^x via single HW instruction (v_exp_f32)
static __device__ __forceinline__ float exp2_hw(float x) {
    float r;
    asm("v_exp_f32 %0, %1" : "=v"(r) : "v"(x));
    return r;
}

// ---------------- prep: cvt_x | cvt_fcW | hist (+per-edge slot) by blockIdx range
__global__ __launch_bounds__(256) void prep_kernel(const float* __restrict__ x,
                                                   unsigned short* __restrict__ xb,
                                                   const float* __restrict__ fcW,
                                                   unsigned short* __restrict__ fcWb,
                                                   const int* __restrict__ dstp,
                                                   int* __restrict__ deg,
                                                   int* __restrict__ posin) {
    int bid = blockIdx.x;
    int tid = threadIdx.x;
    if (bid < CVTX_B) {
        // ---- x fp32 -> bf16
        int t = bid * 256 + tid;
        const float4* in4 = (const float4*)x;
        float4 a = in4[2 * t], b = in4[2 * t + 1];
        ushort8 o;
        o[0] = f2bf(a.x); o[1] = f2bf(a.y); o[2] = f2bf(a.z); o[3] = f2bf(a.w);
        o[4] = f2bf(b.x); o[5] = f2bf(b.y); o[6] = f2bf(b.z); o[7] = f2bf(b.w);
        *reinterpret_cast<ushort8*>(&xb[8 * t]) = o;
    } else if (bid < CVTX_B + CVTW_B) {
        // ---- fcW fp32 -> bf16
        int t = (bid - CVTX_B) * 256 + tid;
        const float4* in4 = (const float4*)fcW;
        float4 a = in4[2 * t], b = in4[2 * t + 1];
        ushort8 o;
        o[0] = f2bf(a.x); o[1] = f2bf(a.y); o[2] = f2bf(a.z); o[3] = f2bf(a.w);
        o[4] = f2bf(b.x); o[5] = f2bf(b.y); o[6] = f2bf(b.z); o[7] = f2bf(b.w);
        *reinterpret_cast<ushort8*>(&fcWb[8 * t]) = o;
    } else {
        // ---- dst-degree histogram; atomic return value = within-node slot
        int e = (bid - CVTX_B - CVTW_B) * 256 + tid;
        int d = dstp[e];
        posin[e] = atomicAdd(&deg[d], 1);
    }
}

// ---------------- proj via MFMA: [eq|ek] = emb @ [Wq;Wk]^T, prescaled -> bf16
// A = emb [128 x 64] bf16 (cvt in staging), B = [Wq;Wk] [128 n x 64 k] bf16.
// Same tile/swizzle structure as fc_mfma; one K-step (K=64).
__global__ __launch_bounds__(256) void proj_mfma(const float* __restrict__ emb,
                                                 const float* __restrict__ Wq,
                                                 const float* __restrict__ Wk,
                                                 unsigned short* __restrict__ eqb,
                                                 unsigned short* __restrict__ ekb) {
    __shared__ unsigned short As[128 * 64];   // 16 KB, swizzled [r][k]
    __shared__ unsigned short Bs[128 * 64];   // 16 KB, swizzled [n][k]
    int tid = threadIdx.x;
    int wave = tid >> 6, lane = tid & 63;
    int wm = wave >> 1, wn = wave & 1;
    int row0 = blockIdx.x * 128;

#pragma unroll
    for (int c = 0; c < 4; ++c) {
        int idx = (c * 256 + tid) * 8;       // element idx in 128x64 tile
        int r = idx >> 6, k = idx & 63;
        int byte = (r * 128 + k * 2) ^ ((r & 7) << 4);

        int node = row0 + r;
        ushort8 o = {};
        if (node < N_NODES) {
            const float4* p = (const float4*)(emb + (size_t)node * DD + k);
            float4 a = p[0], b = p[1];
            o[0] = f2bf(a.x); o[1] = f2bf(a.y); o[2] = f2bf(a.z); o[3] = f2bf(a.w);
            o[4] = f2bf(b.x); o[5] = f2bf(b.y); o[6] = f2bf(b.z); o[7] = f2bf(b.w);
        }
        *reinterpret_cast<ushort8*>(reinterpret_cast<char*>(As) + byte) = o;

        const float* wsrc = (r < 64) ? (Wq + r * DD + k) : (Wk + (r - 64) * DD + k);
        float4 wa = *(const float4*)wsrc, wb = *((const float4*)wsrc + 1);
        ushort8 ow;
        ow[0] = f2bf(wa.x); ow[1] = f2bf(wa.y); ow[2] = f2bf(wa.z); ow[3] = f2bf(wa.w);
        ow[4] = f2bf(wb.x); ow[5] = f2bf(wb.y); ow[6] = f2bf(wb.z); ow[7] = f2bf(wb.w);
        *reinterpret_cast<ushort8*>(reinterpret_cast<char*>(Bs) + byte) = ow;
    }
    __syncthreads();

    f32x4 acc[4][4] = {};
#pragma unroll
    for (int kk = 0; kk < 2; ++kk) {
        bf16x8 a[4], b[4];
#pragma unroll
        for (int m = 0; m < 4; ++m) {
            int r = wm * 64 + m * 16 + (lane & 15);
            int k = kk * 32 + (lane >> 4) * 8;
            int byte = (r * 128 + k * 2) ^ ((r & 7) << 4);
            a[m] = *reinterpret_cast<bf16x8*>(reinterpret_cast<char*>(As) + byte);
        }
#pragma unroll
        for (int n = 0; n < 4; ++n) {
            int cn = wn * 64 + n * 16 + (lane & 15);
            int k = kk * 32 + (lane >> 4) * 8;
            int byte = (cn * 128 + k * 2) ^ ((cn & 7) << 4);
            b[n] = *reinterpret_cast<bf16x8*>(reinterpret_cast<char*>(Bs) + byte);
        }
#pragma unroll
        for (int m = 0; m < 4; ++m)
#pragma unroll
            for (int n = 0; n < 4; ++n)
                acc[m][n] = __builtin_amdgcn_mfma_f32_16x16x32_bf16(a[m], b[n], acc[m][n], 0, 0, 0);
    }

    // C/D: col = lane&15, row = (lane>>4)*4 + j.  cols 0..63 -> eq, 64..127 -> ek
#pragma unroll
    for (int m = 0; m < 4; ++m) {
#pragma unroll
        for (int n = 0; n < 4; ++n) {
            int col = wn * 64 + n * 16 + (lane & 15);
#pragma unroll
            for (int j = 0; j < 4; ++j) {
                int row = row0 + wm * 64 + m * 16 + (lane >> 4) * 4 + j;
                if (row < N_NODES) {
                    unsigned short val = f2bf(PRESCALE * acc[m][n][j]);
                    if (col < 64) eqb[(size_t)row * DD + col] = val;
                    else          ekb[(size_t)row * DD + col - 64] = val;
                }
            }
        }
    }
}

// ---------------- CSR build: histogram -> scan -> scatter
__global__ void scan_reduce(const int* __restrict__ deg, int* __restrict__ bsum) {
    __shared__ int sh[SCAN_B];
    int i = blockIdx.x * SCAN_B + threadIdx.x;
    sh[threadIdx.x] = (i < N_NODES) ? deg[i] : 0;
    __syncthreads();
    for (int s = SCAN_B / 2; s; s >>= 1) {
        if (threadIdx.x < s) sh[threadIdx.x] += sh[threadIdx.x + s];
        __syncthreads();
    }
    if (threadIdx.x == 0) bsum[blockIdx.x] = sh[0];
}

// parallel exclusive scan over NBLK block sums (single 256-thread block)
__global__ void scan_bsum(int* __restrict__ bsum) {
    __shared__ int sh[SCAN_B];
    int tid = threadIdx.x;
    int v = (tid < NBLK) ? bsum[tid] : 0;
    sh[tid] = v;
    __syncthreads();
    for (int s = 1; s < SCAN_B; s <<= 1) {
        int t = (tid >= s) ? sh[tid - s] : 0;
        __syncthreads();
        sh[tid] += t;
        __syncthreads();
    }
    if (tid < NBLK) bsum[tid] = sh[tid] - v;   // exclusive
}

__global__ void scan_final(const int* __restrict__ deg, const int* __restrict__ bsum,
                           int* __restrict__ rowptr) {
    __shared__ int sh[SCAN_B];
    int i = blockIdx.x * SCAN_B + threadIdx.x;
    int v = (i < N_NODES) ? deg[i] : 0;
    sh[threadIdx.x] = v;
    __syncthreads();
    for (int s = 1; s < SCAN_B; s <<= 1) {
        int t = 0;
        if ((int)threadIdx.x >= s) t = sh[threadIdx.x - s];
        __syncthreads();
        sh[threadIdx.x] += t;
        __syncthreads();
    }
    if (i < N_NODES) {
        int excl = sh[threadIdx.x] - v + bsum[blockIdx.x];
        rowptr[i] = excl;
        if (i == N_NODES - 1) rowptr[N_NODES] = excl + v;
    }
}

// atomic-free scatter: slot was captured during hist
__global__ void scatter_kernel(const int* __restrict__ src, const int* __restrict__ dst,
                               const int* __restrict__ rowptr, const int* __restrict__ posin,
                               int* __restrict__ src_sorted) {
    int e = blockIdx.x * blockDim.x + threadIdx.x;
    if (e >= N_EDGES) return;
    int pos = rowptr[dst[e]] + posin[e];
    src_sorted[pos] = src[e];
}

// ---------------- Fused score + softmax + aggregation.
// One wave per dst node; 4 edges/iter, one per 16-lane group.
// Score: lane hl handles dims 4hl..4hl+3; Σv·tanh = Vtot − 2Σv·r with
// r = 1/(exp2(eq2+ek2)+1); 4-step shfl reduce within the group.
// Agg: lane hl holds feats 8hl..8hl+7 (16B) per batch, f32x2 packed FMA.
__global__ __launch_bounds__(256) void agg_fused(const unsigned short* __restrict__ eqb,
                                                 const unsigned short* __restrict__ ekb,
                                                 const float* __restrict__ v,
                                                 const unsigned short* __restrict__ xb,
                                                 const int* __restrict__ rowptr,
                                                 const int* __restrict__ src_sorted,
                                                 unsigned short* __restrict__ aggb) {
    int node = (blockIdx.x * 256 + threadIdx.x) >> 6;
    if (node >= N_NODES) return;
    int lane = threadIdx.x & 63;
    int g = lane >> 4, hl = lane & 15;

    uint2 eku = *reinterpret_cast<const uint2*>(ekb + (size_t)node * DD + 4 * hl);
    float k0 = bf_lo(eku.x), k1 = bf_hi(eku.x), k2 = bf_lo(eku.y), k3 = bf_hi(eku.y);
    float4 vv = *reinterpret_cast<const float4*>(v + 4 * hl);
    float vs = vv.x + vv.y + vv.z + vv.w;
    vs += __shfl_xor(vs, 1); vs += __shfl_xor(vs, 2);
    vs += __shfl_xor(vs, 4); vs += __shfl_xor(vs, 8);
    float vtotl2 = vs * L2E;

    int beg = rowptr[node], end = rowptr[node + 1];
    int nIter = (end - beg + 3) >> 2;

    float sum = 0.f;
    f32x2 a0[4] = {}, a1[4] = {};

    for (int i = 0; i < nIter; ++i) {
        int p = beg + 4 * i + g;
        bool valid = p < end;
        int pe = valid ? p : end - 1;
        int s = src_sorted[pe];

        uint2 equ = *reinterpret_cast<const uint2*>(eqb + (size_t)s * DD + 4 * hl);
        float s0 = bf_lo(equ.x) + k0, s1 = bf_hi(equ.x) + k1;
        float s2 = bf_lo(equ.y) + k2, s3 = bf_hi(equ.y) + k3;
        float r =      vv.x * __builtin_amdgcn_rcpf(exp2_hw(s0) + 1.f);
        r = fmaf(vv.y, __builtin_amdgcn_rcpf(exp2_hw(s1) + 1.f), r);
        r = fmaf(vv.z, __builtin_amdgcn_rcpf(exp2_hw(s2) + 1.f), r);
        r = fmaf(vv.w, __builtin_amdgcn_rcpf(exp2_hw(s3) + 1.f), r);
        r += __shfl_xor(r, 1); r += __shfl_xor(r, 2);
        r += __shfl_xor(r, 4); r += __shfl_xor(r, 8);
        float w = exp2_hw(fmaf(-2.f * L2E, r, vtotl2));
        w = valid ? w : 0.f;
        sum += w;

        uint4 u0 = *reinterpret_cast<const uint4*>(xb + (size_t)s * WFEAT + 8 * hl);
        uint4 u1 = *reinterpret_cast<const uint4*>(xb + (size_t)(N_NODES + s) * WFEAT + 8 * hl);
        a0[0] += w * up2(u0.x); a0[1] += w * up2(u0.y);
        a0[2] += w * up2(u0.z); a0[3] += w * up2(u0.w);
        a1[0] += w * up2(u1.x); a1[1] += w * up2(u1.y);
        a1[2] += w * up2(u1.z); a1[3] += w * up2(u1.w);
    }

    // combine the four 16-lane groups
    sum += __shfl_xor(sum, 16); sum += __shfl_xor(sum, 32);
#pragma unroll
    for (int j = 0; j < 4; ++j) {
        a0[j].x += __shfl_xor(a0[j].x, 16); a0[j].x += __shfl_xor(a0[j].x, 32);
        a0[j].y += __shfl_xor(a0[j].y, 16); a0[j].y += __shfl_xor(a0[j].y, 32);
        a1[j].x += __shfl_xor(a1[j].x, 16); a1[j].x += __shfl_xor(a1[j].x, 32);
        a1[j].y += __shfl_xor(a1[j].y, 16); a1[j].y += __shfl_xor(a1[j].y, 32);
    }
    float inv = __builtin_amdgcn_rcpf(sum + 1e-8f);

    if (g < 2) {
        float c0 = (g ? a1[0].x : a0[0].x) * inv, c1 = (g ? a1[0].y : a0[0].y) * inv;
        float c2 = (g ? a1[1].x : a0[1].x) * inv, c3 = (g ? a1[1].y : a0[1].y) * inv;
        float c4 = (g ? a1[2].x : a0[2].x) * inv, c5 = (g ? a1[2].y : a0[2].y) * inv;
        float c6 = (g ? a1[3].x : a0[3].x) * inv, c7 = (g ? a1[3].y : a0[3].y) * inv;
        uint4 o;
        o.x = (unsigned int)f2bf(c0) | ((unsigned int)f2bf(c1) << 16);
        o.y = (unsigned int)f2bf(c2) | ((unsigned int)f2bf(c3) << 16);
        o.z = (unsigned int)f2bf(c4) | ((unsigned int)f2bf(c5) << 16);
        o.w = (unsigned int)f2bf(c6) | ((unsigned int)f2bf(c7) << 16);
        size_t row = g ? (size_t)(N_NODES + node) : (size_t)node;
        *reinterpret_cast<uint4*>(&aggb[row * WFEAT + 8 * hl]) = o;
    }
}

// ---------------- out = relu([x, agg] @ fcW^T + fcb) via bf16 MFMA
__global__ __launch_bounds__(256) void fc_mfma(const unsigned short* __restrict__ xb,
                                               const unsigned short* __restrict__ aggb,
                                               const unsigned short* __restrict__ fcWb,
                                               const float* __restrict__ fcb,
                                               float* __restrict__ out) {
    __shared__ unsigned short As[128 * 64];   // 16 KB, swizzled [r][k]
    __shared__ unsigned short Bs[128 * 64];   // 16 KB, swizzled [n][k]
    int tid = threadIdx.x;
    int wave = tid >> 6, lane = tid & 63;
    int wm = wave >> 1, wn = wave & 1;
    int row0 = blockIdx.x * 128;

    f32x4 acc[4][4] = {};

    for (int ks = 0; ks < 4; ++ks) {
        const unsigned short* Asrc = (ks < 2) ? xb : aggb;
        int kbase = (ks & 1) * 64;
        __syncthreads();
#pragma unroll
        for (int c = 0; c < 4; ++c) {
            int idx = (c * 256 + tid) * 8;       // element idx in 128x64 tile
            int r = idx >> 6, k = idx & 63;
            int row = row0 + r;
            ulonglong2 val = make_ulonglong2(0ull, 0ull);
            if (row < NROWS)
                val = *reinterpret_cast<const ulonglong2*>(&Asrc[(size_t)row * WFEAT + kbase + k]);
            int byte = (r * 128 + k * 2) ^ ((r & 7) << 4);
            *reinterpret_cast<ulonglong2*>(reinterpret_cast<char*>(As) + byte) = val;

            ulonglong2 wv = *reinterpret_cast<const ulonglong2*>(&fcWb[(size_t)r * 256 + ks * 64 + k]);
            *reinterpret_cast<ulonglong2*>(reinterpret_cast<char*>(Bs) + byte) = wv;
        }
        __syncthreads();
#pragma unroll
        for (int kk = 0; kk < 2; ++kk) {
            bf16x8 a[4], b[4];
#pragma unroll
            for (int m = 0; m < 4; ++m) {
                int r = wm * 64 + m * 16 + (lane & 15);
                int k = kk * 32 + (lane >> 4) * 8;
                int byte = (r * 128 + k * 2) ^ ((r & 7) << 4);
                a[m] = *reinterpret_cast<bf16x8*>(reinterpret_cast<char*>(As) + byte);
            }
#pragma unroll
            for (int n = 0; n < 4; ++n) {
                int cn = wn * 64 + n * 16 + (lane & 15);
                int k = kk * 32 + (lane >> 4) * 8;
                int byte = (cn * 128 + k * 2) ^ ((cn & 7) << 4);
                b[n] = *reinterpret_cast<bf16x8*>(reinterpret_cast<char*>(Bs) + byte);
            }
#pragma unroll
            for (int m = 0; m < 4; ++m)
#pragma unroll
                for (int n = 0; n < 4; ++n)
                    acc[m][n] = __builtin_amdgcn_mfma_f32_16x16x32_bf16(a[m], b[n], acc[m][n], 0, 0, 0);
        }
    }
    // C/D layout: col = lane&15, row = (lane>>4)*4 + j
#pragma unroll
    for (int m = 0; m < 4; ++m) {
#pragma unroll
        for (int n = 0; n < 4; ++n) {
            int col = wn * 64 + n * 16 + (lane & 15);
            float bias = fcb[col];
#pragma unroll
            for (int j = 0; j < 4; ++j) {
                int row = row0 + wm * 64 + m * 16 + (lane >> 4) * 4 + j;
                if (row < NROWS)
                    out[(size_t)row * OUTD + col] = fmaxf(acc[m][n][j] + bias, 0.f);
            }
        }
    }
}

extern "C" void kernel_launch(void* const* d_in, const int* in_sizes, int n_in,
                              void* d_out, int out_size, void* d_ws, size_t ws_size,
                              hipStream_t stream) {
    const float* x    = (const float*)d_in[0];
    const float* emb  = (const float*)d_in[1];
    const int*   eidx = (const int*)d_in[2];
    const float* Wq   = (const float*)d_in[3];
    const float* Wk   = (const float*)d_in[4];
    const float* v    = (const float*)d_in[5];
    const float* fcW  = (const float*)d_in[6];
    const float* fcb  = (const float*)d_in[7];
    float* out = (float*)d_out;

    char* ws = (char*)d_ws;
    unsigned short* eqb  = (unsigned short*)ws;                  ws += (size_t)N_NODES * DD * 2;
    unsigned short* ekb  = (unsigned short*)ws;                  ws += (size_t)N_NODES * DD * 2;
    unsigned short* xb   = (unsigned short*)ws;                  ws += (size_t)NROWS * WFEAT * 2;
    unsigned short* aggb = (unsigned short*)ws;                  ws += (size_t)NROWS * WFEAT * 2;
    unsigned short* fcWb = (unsigned short*)ws;                  ws += (size_t)OUTD * 256 * 2;
    int* deg        = (int*)ws;                                  ws += (size_t)N_NODES * 4;
    int* rowptr     = (int*)ws;                                  ws += (size_t)(N_NODES + 1) * 4 + 12;
    int* posin      = (int*)ws;                                  ws += (size_t)N_EDGES * 4;
    int* bsum       = (int*)ws;                                  ws += 256 * 4;
    int* src_sorted = (int*)ws;

    const int* srcp = eidx;
    const int* dstp = eidx + N_EDGES;

    hipMemsetAsync(deg, 0, (size_t)N_NODES * sizeof(int), stream);

    prep_kernel<<<PREP_B, 256, 0, stream>>>(x, xb, fcW, fcWb, dstp, deg, posin);
    proj_mfma<<<PROJ_TB, 256, 0, stream>>>(emb, Wq, Wk, eqb, ekb);
    scan_reduce<<<NBLK, SCAN_B, 0, stream>>>(deg, bsum);
    scan_bsum<<<1, SCAN_B, 0, stream>>>(bsum);
    scan_final<<<NBLK, SCAN_B, 0, stream>>>(deg, bsum, rowptr);
    scatter_kernel<<<(N_EDGES + 255) / 256, 256, 0, stream>>>(srcp, dstp, rowptr, posin,
                                                              src_sorted);
    agg_fused<<<(N_NODES * 64 + 255) / 256, 256, 0, stream>>>(eqb, ekb, v, xb, rowptr,
                                                              src_sorted, aggb);
    fc_mfma<<<(NROWS + 127) / 128, 256, 0, stream>>>(xb, aggb, fcWb, fcb, out);
}